// Round 7
// baseline (235.875 us; speedup 1.0000x reference)
//
#include <hip/hip_runtime.h>
#include <hip/hip_bf16.h>

typedef __bf16 bf16x8 __attribute__((ext_vector_type(8)));
typedef float  f32x4  __attribute__((ext_vector_type(4)));
typedef float  f32x16 __attribute__((ext_vector_type(16)));

#define LOG2E 1.4426950408889634f
#define N4096 4096
#define NT 64

__device__ __forceinline__ void gl_lds16(const void* g, void* l) {
  __builtin_amdgcn_global_load_lds(
      (const __attribute__((address_space(1))) void*)g,
      (__attribute__((address_space(3))) void*)l, 16, 0, 0);
}

__device__ __forceinline__ void bar() {
  asm volatile("" ::: "memory");
  __builtin_amdgcn_s_barrier();
  asm volatile("" ::: "memory");
}

// ------- K1: blocks 0..511 = zproj (2 rows/wave, named f32x4 accs)
//         + zero qacc/piacc; blocks 512..4607 = transpose x -> XFT bf16.
__global__ __launch_bounds__(256) void xpass_kernel(
    const float* __restrict__ x, const float* __restrict__ pw,
    const float* __restrict__ pb,
    float* __restrict__ z, float* __restrict__ sq,
    float* __restrict__ qacc, float* __restrict__ piacc,
    __hip_bfloat16* __restrict__ xft)
{
  __shared__ float t[64][65];
  int tid = threadIdx.x;
  if (blockIdx.x >= 512) {
    int bidx = blockIdx.x - 512;
    int bk = bidx & 63, bn = bidx >> 6;
    int c = tid & 63, r4 = tid >> 6;
    const float* src = x + (size_t)(bk * 64 + r4) * N4096 + bn * 64 + c;
#pragma unroll
    for (int p = 0; p < 16; ++p)
      t[r4 + p * 4][c] = src[(size_t)p * 4 * N4096];
    __syncthreads();
    __hip_bfloat16* dst = xft + (size_t)(bn * 64 + r4) * N4096 + bk * 64 + c;
#pragma unroll
    for (int p = 0; p < 16; ++p)
      dst[(size_t)p * 4 * N4096] = __float2bfloat16(t[c][r4 + p * 4]);
  } else {
    if (tid < 8) {
      int idx = blockIdx.x * 8 + tid;
      qacc[idx] = 0.f;
      piacc[idx] = 0.f;
    }
    int wv = tid >> 6, lane = tid & 63;
    int row0 = blockIdx.x * 8 + wv * 2;
    const float* xr0 = x + (size_t)row0 * N4096;
    const float* xr1 = xr0 + N4096;
    f32x4 a0 = {0,0,0,0}, b0 = {0,0,0,0}, c0 = {0,0,0,0}, d0 = {0,0,0,0};
    f32x4 a1 = {0,0,0,0}, b1 = {0,0,0,0}, c1 = {0,0,0,0}, d1 = {0,0,0,0};
    for (int k = lane; k < N4096; k += 64) {
      const f32x4* wp = (const f32x4*)(pw + (size_t)k * 16);
      f32x4 wa = wp[0], wb = wp[1], wc = wp[2], wd = wp[3];
      float x0 = xr0[k], x1 = xr1[k];
      a0 += wa * x0; b0 += wb * x0; c0 += wc * x0; d0 += wd * x0;
      a1 += wa * x1; b1 += wb * x1; c1 += wc * x1; d1 += wd * x1;
    }
#define RED4(v)                                                                \
    { _Pragma("unroll") for (int c_ = 0; c_ < 4; ++c_) {                       \
        float s_ = v[c_];                                                      \
        _Pragma("unroll") for (int o_ = 32; o_; o_ >>= 1)                      \
          s_ += __shfl_xor(s_, o_, 64);                                        \
        v[c_] = s_; } }
    RED4(a0); RED4(b0); RED4(c0); RED4(d0);
    RED4(a1); RED4(b1); RED4(c1); RED4(d1);
#undef RED4
    const f32x4* pbq = (const f32x4*)pb;
    f32x4 pa = pbq[0], pbv = pbq[1], pc = pbq[2], pd = pbq[3];
    a0 += pa; b0 += pbv; c0 += pc; d0 += pd;
    a1 += pa; b1 += pbv; c1 += pc; d1 += pd;
    if (lane == 0) {
      f32x4* z0 = (f32x4*)(z + (size_t)row0 * 16);
      z0[0] = a0; z0[1] = b0; z0[2] = c0; z0[3] = d0;
      z0[4] = a1; z0[5] = b1; z0[6] = c1; z0[7] = d1;
      f32x4 s0 = a0*a0 + b0*b0 + c0*c0 + d0*d0;
      f32x4 s1 = a1*a1 + b1*b1 + c1*c1 + d1*d1;
      sq[row0]     = s0[0] + s0[1] + s0[2] + s0[3];
      sq[row0 + 1] = s1[0] + s1[1] + s1[2] + s1[3];
    }
  }
}

// ------- K2: qpi — thread owns one i-row; j-chunk (128) staged in LDS.
__global__ __launch_bounds__(256) void qpi_kernel(
    const float* __restrict__ z, const float* __restrict__ sq,
    const float* __restrict__ w1, const float* __restrict__ b1,
    const float* __restrict__ w2,
    float* __restrict__ qacc, float* __restrict__ piacc)
{
  __shared__ float zjl[128 * 16];
  __shared__ float w1t[128 * 16];
  __shared__ float meta[128 * 4];
  int tid = threadIdx.x;
  int it = blockIdx.x >> 5, jc = blockIdx.x & 31;
  int i  = it * 256 + tid;
  int j0 = jc * 128;
  {
    f32x4* zd = (f32x4*)zjl;
    const f32x4* zs = (const f32x4*)(z + (size_t)j0 * 16);
    zd[tid] = zs[tid];
    zd[tid + 256] = zs[tid + 256];
#pragma unroll
    for (int k = 0; k < 8; ++k) {
      int idx = tid + k * 256;
      int jj = idx >> 4, l = idx & 15;
      w1t[jj * 16 + l] = w1[(size_t)l * N4096 + j0 + jj];
    }
    if (tid < 128) {
      meta[tid * 4 + 0] = sq[j0 + tid];
      meta[tid * 4 + 1] = b1[j0 + tid];
      meta[tid * 4 + 2] = w2[j0 + tid];
      meta[tid * 4 + 3] = 0.f;
    }
  }
  __syncthreads();
  const f32x4* ziq = (const f32x4*)(z + (size_t)i * 16);
  f32x4 zi0 = ziq[0], zi1 = ziq[1], zi2 = ziq[2], zi3 = ziq[3];
  float sqi = sq[i];
  float accq = 0.f, accp = 0.f;
  for (int jj = 0; jj < 128; ++jj) {
    const f32x4* zq = (const f32x4*)(zjl + jj * 16);
    f32x4 za = zq[0], zb = zq[1], zc = zq[2], zd = zq[3];
    const f32x4* wq = (const f32x4*)(w1t + jj * 16);
    f32x4 wa = wq[0], wb = wq[1], wc = wq[2], wd = wq[3];
    f32x4 me = *(const f32x4*)(meta + jj * 4);
    f32x4 dz4 = zi0 * za + zi1 * zb + zi2 * zc + zi3 * zd;
    float dz = dz4[0] + dz4[1] + dz4[2] + dz4[3];
    f32x4 dw4 = zi0 * wa + zi1 * wb + zi2 * wc + zi3 * wd;
    float dw = dw4[0] + dw4[1] + dw4[2] + dw4[3];
    accq += exp2f(-LOG2E * (sqi + me[0] - 2.f * dz));
    accp += fmaxf(dw + me[1], 0.f) * me[2];
  }
  atomicAdd(&qacc[i], accq);
  atomicAdd(&piacc[i], accp);
}

// ------- K3: W[i][j] = bf16(exp(-d2)*dvec[j]) — dvec computed inline. --------
__global__ __launch_bounds__(256) void wmat_kernel(
    const float* __restrict__ z, const float* __restrict__ sq,
    const float* __restrict__ qacc, const float* __restrict__ piacc,
    const float* __restrict__ b2p, __hip_bfloat16* __restrict__ W)
{
  __shared__ float zil[64 * 16];
  __shared__ float sqil[64];
  int tid = threadIdx.x;
  int it = blockIdx.x >> 3, jc = blockIdx.x & 7;
  int i0 = it * 64, j0 = jc * 512;
  ((f32x4*)zil)[tid] = *(const f32x4*)(z + (size_t)i0 * 16 + tid * 4);
  if (tid < 64) sqil[tid] = sq[i0 + tid];
  __syncthreads();
  int j = j0 + tid * 2;
  const f32x4* zjq = (const f32x4*)(z + (size_t)j * 16);
  f32x4 u0 = zjq[0], u1 = zjq[1], u2 = zjq[2], u3 = zjq[3];
  f32x4 v0 = zjq[4], v1 = zjq[5], v2 = zjq[6], v3 = zjq[7];
  float sq0 = sq[j], sq1 = sq[j + 1];
  float b2 = b2p[0];
  float dv0 = (1.f / (1.f + exp2f(-LOG2E * (piacc[j] + b2)))) / qacc[j];
  float dv1 = (1.f / (1.f + exp2f(-LOG2E * (piacc[j + 1] + b2)))) / qacc[j + 1];
  for (int ii = 0; ii < 64; ++ii) {
    const f32x4* zq = (const f32x4*)(zil + ii * 16);
    f32x4 a = zq[0], b = zq[1], c = zq[2], d = zq[3];
    f32x4 t0 = a * u0 + b * u1 + c * u2 + d * u3;
    f32x4 t1 = a * v0 + b * v1 + c * v2 + d * v3;
    float dz0 = t0[0] + t0[1] + t0[2] + t0[3];
    float dz1 = t1[0] + t1[1] + t1[2] + t1[3];
    float sqi = sqil[ii];
    float w0 = exp2f(-LOG2E * (sqi + sq0 - 2.f * dz0)) * dv0;
    float w1v = exp2f(-LOG2E * (sqi + sq1 - 2.f * dz1)) * dv1;
    __hip_bfloat162 pk;
    pk.x = __float2bfloat16(w0);
    pk.y = __float2bfloat16(w1v);
    *(__hip_bfloat162*)(W + (size_t)(i0 + ii) * N4096 + j) = pk;
  }
}

// ------- K4: D row-sum of bf16 W (wave/row) -> rowscale + diag-fold -----------
__global__ __launch_bounds__(256) void rsdiag_kernel(
    __hip_bfloat16* __restrict__ W, const float* __restrict__ qacc,
    const float* __restrict__ piacc, const float* __restrict__ b2p,
    const float* __restrict__ dtp, float* __restrict__ rowscale)
{
  int tid = threadIdx.x;
  int wv = tid >> 6, lane = tid & 63;
  int row = blockIdx.x * 4 + wv;
  const uint4* p = (const uint4*)(W + (size_t)row * N4096);
  float s = 0.f;
#pragma unroll
  for (int k = 0; k < 8; ++k) {
    uint4 u = p[lane + k * 64];
#pragma unroll
    for (int c = 0; c < 4; ++c) {
      unsigned w = (&u.x)[c];
      union { unsigned u32; float f; } lo, hi;
      lo.u32 = w << 16;
      hi.u32 = w & 0xFFFF0000u;
      s += lo.f + hi.f;
    }
  }
#pragma unroll
  for (int o = 32; o; o >>= 1) s += __shfl_xor(s, o, 64);
  if (lane == 0) {
    float dtv = dtp[0];
    float Dp = s + 1e-5f;
    rowscale[row] = 4.f * dtv / Dp;
    float dv = (1.f / (1.f + exp2f(-LOG2E * (piacc[row] + b2p[0])))) / qacc[row];
    W[(size_t)row * N4096 + row] =
        __float2bfloat16(dv + (1.f - dtv) * Dp / (4.f * dtv));
  }
}

// ---------------- K5: out = rowscale[i] * (W' @ XFT^T) ------------------------
// 256x256 tile, BK=64, 8 waves (2Mx4N), round-2 barrier/staging protocol,
// 32x32x16 MFMA. Swizzle fix: swz(row) = (row&7) ^ ((row>>2)&4) — folds row
// bit4 into slot bit2 so lanes l and l+16 (quarter-wave co-issue) never share
// a bank quad. Applied identically to staging source and both read sides.
__global__ __launch_bounds__(512, 2) void gemm32_kernel(
    const __hip_bfloat16* __restrict__ Wm, const __hip_bfloat16* __restrict__ BT,
    const float* __restrict__ rowscale, float* __restrict__ out)
{
  extern __shared__ __bf16 S[];   // [2 bufs][A 16384 | B 16384] = 128 KB
  const int b0 = blockIdx.x;
  const int xcd = b0 & 7, idx = b0 >> 3;
  const int tm = (xcd >> 1) * 4 + (idx & 3);   // 4-row band per XCD pair
  const int tn = (xcd & 1) * 8 + (idx >> 2);   // 8-col half
  const int tid = threadIdx.x;
  const int lane = tid & 63;
  const int wv = tid >> 6;
  const int wr = wv >> 2, wc = wv & 3;         // 2 x 4 waves
  const int hi = lane >> 5, l31 = lane & 31;

  const int srow = tid >> 3;                   // 0..63 within a 64-row unit
  const int lslot = tid & 7;                   // linear LDS slot (8 bf16 each)

  const __hip_bfloat16* Abase = Wm + (size_t)(tm * 256) * N4096;
  const __hip_bfloat16* Bbase = BT + (size_t)(tn * 256) * N4096;

#define SWZ(r_) (((r_) & 7) ^ (((r_) >> 2) & 4))

  auto stageA = [&](int tk, int R0) {
    int r = R0 + srow;
    int gc = lslot ^ SWZ(r);                   // pre-swizzled global source
    gl_lds16(Abase + (size_t)r * N4096 + tk * 64 + gc * 8,
             S + (size_t)(tk & 1) * 32768 + r * 64 + lslot * 8);
  };
  auto stageB = [&](int tk, int R0) {
    int r = R0 + srow;
    int gc = lslot ^ SWZ(r);
    gl_lds16(Bbase + (size_t)r * N4096 + tk * 64 + gc * 8,
             S + (size_t)(tk & 1) * 32768 + 16384 + r * 64 + lslot * 8);
  };

  f32x16 acc[4][2];
#pragma unroll
  for (int i = 0; i < 4; ++i)
#pragma unroll
    for (int j = 0; j < 2; ++j)
#pragma unroll
      for (int c = 0; c < 16; ++c) acc[i][j][c] = 0.f;

  // Prologue: tile0 full (8 units), tile1 partial (6 units, steady-state order)
  stageA(0, 0); stageA(0, 64); stageA(0, 128); stageA(0, 192);
  stageB(0, 0); stageB(0, 64); stageB(0, 128); stageB(0, 192);
  stageB(1, 0); stageB(1, 64); stageB(1, 128); stageB(1, 192);
  stageA(1, 0); stageA(1, 128);
  asm volatile("s_waitcnt vmcnt(6)" ::: "memory");
  bar();

  for (int t = 0; t < NT; ++t) {
    const __bf16* sAb = S + (size_t)(t & 1) * 32768;
    const __bf16* sBb = sAb + 16384;
    bf16x8 bfrag[2][4];

#define APHASE(q)                                                              \
    {                                                                          \
      bf16x8 af[4];                                                            \
      _Pragma("unroll")                                                        \
      for (int ks = 0; ks < 4; ++ks) {                                         \
        int row_ = wr * 128 + (q) * 32 + l31;                                  \
        int slot_ = ((ks << 1) | hi) ^ SWZ(row_);                              \
        af[ks] = *(const bf16x8*)(sAb + row_ * 64 + slot_ * 8);                \
      }                                                                        \
      bar();                                                                   \
      __builtin_amdgcn_s_setprio(1);                                          \
      _Pragma("unroll")                                                        \
      for (int ks = 0; ks < 4; ++ks)                                           \
        _Pragma("unroll")                                                      \
        for (int ni = 0; ni < 2; ++ni)                                         \
          acc[(q)][ni] = __builtin_amdgcn_mfma_f32_32x32x16_bf16(              \
              af[ks], bfrag[ni][ks], acc[(q)][ni], 0, 0, 0);                   \
      __builtin_amdgcn_s_setprio(0);                                          \
    }

    // ---- phase 0: stage tile t+1's last two A units; read B + A-band 0
    if (t + 1 < NT) { stageA(t + 1, 64); stageA(t + 1, 192); }
#pragma unroll
    for (int ni = 0; ni < 2; ++ni)
#pragma unroll
      for (int ks = 0; ks < 4; ++ks) {
        int row_ = wc * 64 + ni * 32 + l31;
        int slot_ = ((ks << 1) | hi) ^ SWZ(row_);
        bfrag[ni][ks] = *(const bf16x8*)(sBb + row_ * 64 + slot_ * 8);
      }
    APHASE(0);
    bar();
    // ---- phase 1: B of tile t is dead -> stage tile t+2's B half 0
    if (t + 2 < NT) { stageB(t + 2, 0); stageB(t + 2, 64); }
    APHASE(1);
    bar();
    // ---- phase 2: stage tile t+2's B half 1
    if (t + 2 < NT) { stageB(t + 2, 128); stageB(t + 2, 192); }
    APHASE(2);
    bar();
    // ---- phase 3: A units 0,128 of tile t dead -> stage tile t+2's
    if (t + 2 < NT) { stageA(t + 2, 0); stageA(t + 2, 128); }
    APHASE(3);
    // ---- tile boundary: counted wait (tile t+1 staged; t+2's 6 in flight)
    if (t + 2 < NT)      { asm volatile("s_waitcnt vmcnt(6)" ::: "memory"); }
    else if (t + 1 < NT) { asm volatile("s_waitcnt vmcnt(0)" ::: "memory"); }
    bar();
#undef APHASE
  }
#undef SWZ

  // Epilogue: C layout col=lane&31, row=(r&3)+8*(r>>2)+4*(lane>>5).
#pragma unroll
  for (int mi = 0; mi < 4; ++mi) {
#pragma unroll
    for (int ni = 0; ni < 2; ++ni) {
#pragma unroll
      for (int r = 0; r < 16; ++r) {
        int row = tm * 256 + wr * 128 + mi * 32 + (r & 3) + 8 * (r >> 2) + 4 * hi;
        int col = tn * 256 + wc * 64 + ni * 32 + l31;
        out[(size_t)row * N4096 + col] = rowscale[row] * acc[mi][ni][r];
      }
    }
  }
}

extern "C" void kernel_launch(void* const* d_in, const int* in_sizes, int n_in,
                              void* d_out, int out_size, void* d_ws, size_t ws_size,
                              hipStream_t stream) {
  const float* x      = (const float*)d_in[0];
  const float* proj_w = (const float*)d_in[1];
  const float* proj_b = (const float*)d_in[2];
  const float* pi_w1  = (const float*)d_in[3];
  const float* pi_b1  = (const float*)d_in[4];
  const float* pi_w2  = (const float*)d_in[5];
  const float* pi_b2  = (const float*)d_in[6];
  const float* dt     = (const float*)d_in[7];
  float* out = (float*)d_out;

  char* ws = (char*)d_ws;
  const size_t MB = 1024 * 1024;
  __hip_bfloat16* W   = (__hip_bfloat16*)(ws);               // 32 MB
  __hip_bfloat16* XFT = (__hip_bfloat16*)(ws + 32 * MB);     // 32 MB
  float* z        = (float*)(ws + 64 * MB);                  // 256 KB
  float* sq       = (float*)(ws + 64 * MB + 256 * 1024);     // 16 KB
  float* qacc     = (float*)(ws + 64 * MB + 272 * 1024);     // 16 KB
  float* piacc    = (float*)(ws + 64 * MB + 288 * 1024);     // 16 KB
  float* rowscale = (float*)(ws + 64 * MB + 304 * 1024);     // 16 KB

  (void)hipFuncSetAttribute((const void*)gemm32_kernel,
                            hipFuncAttributeMaxDynamicSharedMemorySize, 131072);

  xpass_kernel<<<4608, 256, 0, stream>>>(x, proj_w, proj_b, z, sq,
                                         qacc, piacc, XFT);
  qpi_kernel<<<512, 256, 0, stream>>>(z, sq, pi_w1, pi_b1, pi_w2, qacc, piacc);
  wmat_kernel<<<512, 256, 0, stream>>>(z, sq, qacc, piacc, pi_b2, W);
  rsdiag_kernel<<<1024, 256, 0, stream>>>(W, qacc, piacc, pi_b2, dt, rowscale);
  gemm32_kernel<<<256, 512, 131072, stream>>>(W, XFT, rowscale, out);
}

// Round 8
// 226.043 us; speedup vs baseline: 1.0435x; 1.0435x over previous
//
#include <hip/hip_runtime.h>
#include <hip/hip_bf16.h>

typedef __bf16 bf16x8 __attribute__((ext_vector_type(8)));
typedef float  f32x4  __attribute__((ext_vector_type(4)));

#define LOG2E 1.4426950408889634f
#define N4096 4096
#define NT 64

__device__ __forceinline__ void gl_lds16(const void* g, void* l) {
  __builtin_amdgcn_global_load_lds(
      (const __attribute__((address_space(1))) void*)g,
      (__attribute__((address_space(3))) void*)l, 16, 0, 0);
}

__device__ __forceinline__ void bar() {
  asm volatile("" ::: "memory");
  __builtin_amdgcn_s_barrier();
  asm volatile("" ::: "memory");
}

// ------- K1: blocks 0..511 = zproj (2 rows/wave, named f32x4 accs)
//         + zero qacc/piacc; blocks 512..4607 = transpose x -> XFT bf16.
__global__ __launch_bounds__(256) void xpass_kernel(
    const float* __restrict__ x, const float* __restrict__ pw,
    const float* __restrict__ pb,
    float* __restrict__ z, float* __restrict__ sq,
    float* __restrict__ qacc, float* __restrict__ piacc,
    __hip_bfloat16* __restrict__ xft)
{
  __shared__ float t[64][65];
  int tid = threadIdx.x;
  if (blockIdx.x >= 512) {
    int bidx = blockIdx.x - 512;
    int bk = bidx & 63, bn = bidx >> 6;
    int c = tid & 63, r4 = tid >> 6;
    const float* src = x + (size_t)(bk * 64 + r4) * N4096 + bn * 64 + c;
#pragma unroll
    for (int p = 0; p < 16; ++p)
      t[r4 + p * 4][c] = src[(size_t)p * 4 * N4096];
    __syncthreads();
    __hip_bfloat16* dst = xft + (size_t)(bn * 64 + r4) * N4096 + bk * 64 + c;
#pragma unroll
    for (int p = 0; p < 16; ++p)
      dst[(size_t)p * 4 * N4096] = __float2bfloat16(t[c][r4 + p * 4]);
  } else {
    if (tid < 8) {
      int idx = blockIdx.x * 8 + tid;
      qacc[idx] = 0.f;
      piacc[idx] = 0.f;
    }
    int wv = tid >> 6, lane = tid & 63;
    int row0 = blockIdx.x * 8 + wv * 2;
    const float* xr0 = x + (size_t)row0 * N4096;
    const float* xr1 = xr0 + N4096;
    f32x4 a0 = {0,0,0,0}, b0 = {0,0,0,0}, c0 = {0,0,0,0}, d0 = {0,0,0,0};
    f32x4 a1 = {0,0,0,0}, b1 = {0,0,0,0}, c1 = {0,0,0,0}, d1 = {0,0,0,0};
    for (int k = lane; k < N4096; k += 64) {
      const f32x4* wp = (const f32x4*)(pw + (size_t)k * 16);
      f32x4 wa = wp[0], wb = wp[1], wc = wp[2], wd = wp[3];
      float x0 = xr0[k], x1 = xr1[k];
      a0 += wa * x0; b0 += wb * x0; c0 += wc * x0; d0 += wd * x0;
      a1 += wa * x1; b1 += wb * x1; c1 += wc * x1; d1 += wd * x1;
    }
#define RED4(v)                                                                \
    { _Pragma("unroll") for (int c_ = 0; c_ < 4; ++c_) {                       \
        float s_ = v[c_];                                                      \
        _Pragma("unroll") for (int o_ = 32; o_; o_ >>= 1)                      \
          s_ += __shfl_xor(s_, o_, 64);                                        \
        v[c_] = s_; } }
    RED4(a0); RED4(b0); RED4(c0); RED4(d0);
    RED4(a1); RED4(b1); RED4(c1); RED4(d1);
#undef RED4
    const f32x4* pbq = (const f32x4*)pb;
    f32x4 pa = pbq[0], pbv = pbq[1], pc = pbq[2], pd = pbq[3];
    a0 += pa; b0 += pbv; c0 += pc; d0 += pd;
    a1 += pa; b1 += pbv; c1 += pc; d1 += pd;
    if (lane == 0) {
      f32x4* z0 = (f32x4*)(z + (size_t)row0 * 16);
      z0[0] = a0; z0[1] = b0; z0[2] = c0; z0[3] = d0;
      z0[4] = a1; z0[5] = b1; z0[6] = c1; z0[7] = d1;
      f32x4 s0 = a0*a0 + b0*b0 + c0*c0 + d0*d0;
      f32x4 s1 = a1*a1 + b1*b1 + c1*c1 + d1*d1;
      sq[row0]     = s0[0] + s0[1] + s0[2] + s0[3];
      sq[row0 + 1] = s1[0] + s1[1] + s1[2] + s1[3];
    }
  }
}

// ------- K2: qpi — thread owns one i-row; j-chunk (128) staged in LDS.
__global__ __launch_bounds__(256) void qpi_kernel(
    const float* __restrict__ z, const float* __restrict__ sq,
    const float* __restrict__ w1, const float* __restrict__ b1,
    const float* __restrict__ w2,
    float* __restrict__ qacc, float* __restrict__ piacc)
{
  __shared__ float zjl[128 * 16];
  __shared__ float w1t[128 * 16];
  __shared__ float meta[128 * 4];
  int tid = threadIdx.x;
  int it = blockIdx.x >> 5, jc = blockIdx.x & 31;
  int i  = it * 256 + tid;
  int j0 = jc * 128;
  {
    f32x4* zd = (f32x4*)zjl;
    const f32x4* zs = (const f32x4*)(z + (size_t)j0 * 16);
    zd[tid] = zs[tid];
    zd[tid + 256] = zs[tid + 256];
#pragma unroll
    for (int k = 0; k < 8; ++k) {
      int idx = tid + k * 256;
      int jj = idx >> 4, l = idx & 15;
      w1t[jj * 16 + l] = w1[(size_t)l * N4096 + j0 + jj];
    }
    if (tid < 128) {
      meta[tid * 4 + 0] = sq[j0 + tid];
      meta[tid * 4 + 1] = b1[j0 + tid];
      meta[tid * 4 + 2] = w2[j0 + tid];
      meta[tid * 4 + 3] = 0.f;
    }
  }
  __syncthreads();
  const f32x4* ziq = (const f32x4*)(z + (size_t)i * 16);
  f32x4 zi0 = ziq[0], zi1 = ziq[1], zi2 = ziq[2], zi3 = ziq[3];
  float sqi = sq[i];
  float accq = 0.f, accp = 0.f;
  for (int jj = 0; jj < 128; ++jj) {
    const f32x4* zq = (const f32x4*)(zjl + jj * 16);
    f32x4 za = zq[0], zb = zq[1], zc = zq[2], zd = zq[3];
    const f32x4* wq = (const f32x4*)(w1t + jj * 16);
    f32x4 wa = wq[0], wb = wq[1], wc = wq[2], wd = wq[3];
    f32x4 me = *(const f32x4*)(meta + jj * 4);
    f32x4 dz4 = zi0 * za + zi1 * zb + zi2 * zc + zi3 * zd;
    float dz = dz4[0] + dz4[1] + dz4[2] + dz4[3];
    f32x4 dw4 = zi0 * wa + zi1 * wb + zi2 * wc + zi3 * wd;
    float dw = dw4[0] + dw4[1] + dw4[2] + dw4[3];
    accq += exp2f(-LOG2E * (sqi + me[0] - 2.f * dz));
    accp += fmaxf(dw + me[1], 0.f) * me[2];
  }
  atomicAdd(&qacc[i], accq);
  atomicAdd(&piacc[i], accp);
}

// ------- K3 (fused wmat+rsdiag): block = 8 rows x all 4096 j.
//   W[i][j] = bf16(exp(-d2)*dvec[j]); per-row D accumulated in registers,
//   reduced in-block; rowscale + diag-fold written by the same block.
__global__ __launch_bounds__(256) void wmat2_kernel(
    const float* __restrict__ z, const float* __restrict__ sq,
    const float* __restrict__ qacc, const float* __restrict__ piacc,
    const float* __restrict__ b2p, const float* __restrict__ dtp,
    __hip_bfloat16* __restrict__ W, float* __restrict__ rowscale)
{
  __shared__ float zil[8 * 16];
  __shared__ float sqil[8];
  __shared__ float red[8][4];
  int tid = threadIdx.x;
  int i0 = blockIdx.x * 8;
  if (tid < 128) zil[tid] = z[(size_t)i0 * 16 + tid];
  if (tid < 8) sqil[tid] = sq[i0 + tid];
  __syncthreads();
  float b2 = b2p[0];
  float Dp0 = 0.f, Dp1 = 0.f, Dp2 = 0.f, Dp3 = 0.f;
  float Dp4 = 0.f, Dp5 = 0.f, Dp6 = 0.f, Dp7 = 0.f;
  for (int c = 0; c < 8; ++c) {
    int j = c * 512 + tid * 2;
    const f32x4* zjq = (const f32x4*)(z + (size_t)j * 16);
    f32x4 u0 = zjq[0], u1 = zjq[1], u2 = zjq[2], u3 = zjq[3];
    f32x4 v0 = zjq[4], v1 = zjq[5], v2 = zjq[6], v3 = zjq[7];
    float sq0 = sq[j], sq1 = sq[j + 1];
    float dv0 = (1.f / (1.f + exp2f(-LOG2E * (piacc[j] + b2)))) / qacc[j];
    float dv1 = (1.f / (1.f + exp2f(-LOG2E * (piacc[j + 1] + b2)))) / qacc[j + 1];
#define WROW(r, DREG)                                                          \
    {                                                                          \
      const f32x4* zq = (const f32x4*)(zil + (r) * 16);                        \
      f32x4 a = zq[0], bb = zq[1], cc = zq[2], dd = zq[3];                     \
      f32x4 t0 = a * u0 + bb * u1 + cc * u2 + dd * u3;                         \
      f32x4 t1 = a * v0 + bb * v1 + cc * v2 + dd * v3;                         \
      float dz0 = t0[0] + t0[1] + t0[2] + t0[3];                               \
      float dz1 = t1[0] + t1[1] + t1[2] + t1[3];                               \
      float sqi = sqil[(r)];                                                   \
      float w0 = exp2f(-LOG2E * (sqi + sq0 - 2.f * dz0)) * dv0;                \
      float w1v = exp2f(-LOG2E * (sqi + sq1 - 2.f * dz1)) * dv1;               \
      __hip_bfloat162 pk;                                                      \
      pk.x = __float2bfloat16(w0);                                             \
      pk.y = __float2bfloat16(w1v);                                            \
      *(__hip_bfloat162*)(W + (size_t)(i0 + (r)) * N4096 + j) = pk;            \
      DREG += w0 + w1v;                                                        \
    }
    WROW(0, Dp0); WROW(1, Dp1); WROW(2, Dp2); WROW(3, Dp3);
    WROW(4, Dp4); WROW(5, Dp5); WROW(6, Dp6); WROW(7, Dp7);
#undef WROW
  }
  int lane = tid & 63, wv = tid >> 6;
#define REDR(r, DREG)                                                          \
  { float v_ = DREG;                                                           \
    _Pragma("unroll") for (int o_ = 32; o_; o_ >>= 1)                          \
      v_ += __shfl_xor(v_, o_, 64);                                            \
    if (lane == 0) red[(r)][wv] = v_; }
  REDR(0, Dp0); REDR(1, Dp1); REDR(2, Dp2); REDR(3, Dp3);
  REDR(4, Dp4); REDR(5, Dp5); REDR(6, Dp6); REDR(7, Dp7);
#undef REDR
  __syncthreads();   // also drains main-loop W stores (vmcnt(0) before barrier)
  if (tid < 8) {
    float dtv = dtp[0];
    float D = red[tid][0] + red[tid][1] + red[tid][2] + red[tid][3] + 1e-5f;
    int i = i0 + tid;
    rowscale[i] = 4.f * dtv / D;
    float dv = (1.f / (1.f + exp2f(-LOG2E * (piacc[i] + b2)))) / qacc[i];
    W[(size_t)i * N4096 + i] =
        __float2bfloat16(dv + (1.f - dtv) * D / (4.f * dtv));
  }
}

// ---------------- K4: out = rowscale[i] * (W' @ XFT^T) ------------------------
// EXACT round-5 gemm8 (16x16x32 MFMA, 0-conflict swizzle, counted vmcnt(6)),
// with rect XCD mapping (4x8 tile rectangle per XCD) for L2 locality.
__global__ __launch_bounds__(512, 2) void gemm8_kernel(
    const __hip_bfloat16* __restrict__ Wm, const __hip_bfloat16* __restrict__ BT,
    const float* __restrict__ rowscale, float* __restrict__ out)
{
  extern __shared__ __bf16 S[];   // [2 bufs][A 16384 | B 16384] = 128 KB
  const int b0 = blockIdx.x;
  const int xcd = b0 & 7, idx = b0 >> 3;
  const int tm = (xcd >> 1) * 4 + (idx & 3);   // 4-row band per XCD pair
  const int tn = (xcd & 1) * 8 + (idx >> 2);   // 8-col half
  const int tid = threadIdx.x;
  const int lane = tid & 63;
  const int wv = tid >> 6;
  const int wr = wv >> 2, wc = wv & 3;         // 2 x 4 waves
  const int g = lane >> 4, rr = lane & 15;

  const int srow = tid >> 3;                   // 0..63 within a 64-row unit
  const int lslot = tid & 7;                   // linear LDS slot (8 bf16 each)

  const __hip_bfloat16* Abase = Wm + (size_t)(tm * 256) * N4096;
  const __hip_bfloat16* Bbase = BT + (size_t)(tn * 256) * N4096;

  auto stageA = [&](int tk, int R0) {
    int r = R0 + srow;
    int gc = lslot ^ (r & 7);                  // pre-swizzled global source
    gl_lds16(Abase + (size_t)r * N4096 + tk * 64 + gc * 8,
             S + (size_t)(tk & 1) * 32768 + r * 64 + lslot * 8);
  };
  auto stageB = [&](int tk, int R0) {
    int r = R0 + srow;
    int gc = lslot ^ (r & 7);
    gl_lds16(Bbase + (size_t)r * N4096 + tk * 64 + gc * 8,
             S + (size_t)(tk & 1) * 32768 + 16384 + r * 64 + lslot * 8);
  };

  f32x4 acc[8][4];
#pragma unroll
  for (int i = 0; i < 8; ++i)
#pragma unroll
    for (int j = 0; j < 4; ++j) acc[i][j] = (f32x4){0.f, 0.f, 0.f, 0.f};

  // Prologue: tile0 full (8 units), tile1 partial (6 units, steady-state order)
  stageA(0, 0); stageA(0, 64); stageA(0, 128); stageA(0, 192);
  stageB(0, 0); stageB(0, 64); stageB(0, 128); stageB(0, 192);
  stageB(1, 0); stageB(1, 64); stageB(1, 128); stageB(1, 192);
  stageA(1, 0); stageA(1, 128);
  asm volatile("s_waitcnt vmcnt(6)" ::: "memory");
  bar();

  for (int t = 0; t < NT; ++t) {
    const __bf16* sAb = S + (size_t)(t & 1) * 32768;
    const __bf16* sBb = sAb + 16384;
    bf16x8 bfrag[4][2];

#define APHASE(q)                                                              \
    {                                                                          \
      bf16x8 af[2][2];                                                         \
      _Pragma("unroll")                                                        \
      for (int mi2 = 0; mi2 < 2; ++mi2) {                                      \
        _Pragma("unroll")                                                      \
        for (int kh = 0; kh < 2; ++kh) {                                       \
          int row_ = wr * 128 + ((q) * 2 + mi2) * 16 + rr;                     \
          int slot_ = ((kh << 2) | g) ^ (rr & 7);                              \
          af[mi2][kh] = *(const bf16x8*)(sAb + row_ * 64 + slot_ * 8);         \
        }                                                                      \
      }                                                                        \
      bar();                                                                   \
      __builtin_amdgcn_s_setprio(1);                                          \
      _Pragma("unroll")                                                        \
      for (int kh = 0; kh < 2; ++kh)                                           \
        _Pragma("unroll")                                                      \
        for (int mi2 = 0; mi2 < 2; ++mi2)                                      \
          _Pragma("unroll")                                                    \
          for (int ni = 0; ni < 4; ++ni)                                       \
            acc[(q) * 2 + mi2][ni] = __builtin_amdgcn_mfma_f32_16x16x32_bf16(  \
                af[mi2][kh], bfrag[ni][kh], acc[(q) * 2 + mi2][ni], 0, 0, 0);  \
      __builtin_amdgcn_s_setprio(0);                                          \
    }

    // ---- phase 0: stage tile t+1's last two A units; read B + A-quadrant 0
    if (t + 1 < NT) { stageA(t + 1, 64); stageA(t + 1, 192); }
#pragma unroll
    for (int ni = 0; ni < 4; ++ni)
#pragma unroll
      for (int kh = 0; kh < 2; ++kh) {
        int row_ = wc * 64 + ni * 16 + rr;
        int slot_ = ((kh << 2) | g) ^ (rr & 7);
        bfrag[ni][kh] = *(const bf16x8*)(sBb + row_ * 64 + slot_ * 8);
      }
    APHASE(0);
    bar();
    // ---- phase 1: B of tile t is dead -> stage tile t+2's B half 0
    if (t + 2 < NT) { stageB(t + 2, 0); stageB(t + 2, 64); }
    APHASE(1);
    bar();
    // ---- phase 2: stage tile t+2's B half 1
    if (t + 2 < NT) { stageB(t + 2, 128); stageB(t + 2, 192); }
    APHASE(2);
    bar();
    // ---- phase 3: A units 0,128 of tile t dead after quadrants 0-1 -> stage
    if (t + 2 < NT) { stageA(t + 2, 0); stageA(t + 2, 128); }
    APHASE(3);
    // ---- tile boundary: counted wait (tile t+1 staged; t+2's 6 in flight)
    if (t + 2 < NT)      { asm volatile("s_waitcnt vmcnt(6)" ::: "memory"); }
    else if (t + 1 < NT) { asm volatile("s_waitcnt vmcnt(0)" ::: "memory"); }
    bar();
#undef APHASE
  }

#pragma unroll
  for (int mi = 0; mi < 8; ++mi) {
#pragma unroll
    for (int r4 = 0; r4 < 4; ++r4) {
      int row = tm * 256 + wr * 128 + mi * 16 + g * 4 + r4;
      float rs = rowscale[row];
      float* orow = out + (size_t)row * N4096;
#pragma unroll
      for (int ni = 0; ni < 4; ++ni) {
        int col = tn * 256 + wc * 64 + ni * 16 + rr;
        orow[col] = rs * acc[mi][ni][r4];
      }
    }
  }
}

extern "C" void kernel_launch(void* const* d_in, const int* in_sizes, int n_in,
                              void* d_out, int out_size, void* d_ws, size_t ws_size,
                              hipStream_t stream) {
  const float* x      = (const float*)d_in[0];
  const float* proj_w = (const float*)d_in[1];
  const float* proj_b = (const float*)d_in[2];
  const float* pi_w1  = (const float*)d_in[3];
  const float* pi_b1  = (const float*)d_in[4];
  const float* pi_w2  = (const float*)d_in[5];
  const float* pi_b2  = (const float*)d_in[6];
  const float* dt     = (const float*)d_in[7];
  float* out = (float*)d_out;

  char* ws = (char*)d_ws;
  const size_t MB = 1024 * 1024;
  __hip_bfloat16* W   = (__hip_bfloat16*)(ws);               // 32 MB
  __hip_bfloat16* XFT = (__hip_bfloat16*)(ws + 32 * MB);     // 32 MB
  float* z        = (float*)(ws + 64 * MB);                  // 256 KB
  float* sq       = (float*)(ws + 64 * MB + 256 * 1024);     // 16 KB
  float* qacc     = (float*)(ws + 64 * MB + 272 * 1024);     // 16 KB
  float* piacc    = (float*)(ws + 64 * MB + 288 * 1024);     // 16 KB
  float* rowscale = (float*)(ws + 64 * MB + 304 * 1024);     // 16 KB

  (void)hipFuncSetAttribute((const void*)gemm8_kernel,
                            hipFuncAttributeMaxDynamicSharedMemorySize, 131072);

  xpass_kernel<<<4608, 256, 0, stream>>>(x, proj_w, proj_b, z, sq,
                                         qacc, piacc, XFT);
  qpi_kernel<<<512, 256, 0, stream>>>(z, sq, pi_w1, pi_b1, pi_w2, qacc, piacc);
  wmat2_kernel<<<512, 256, 0, stream>>>(z, sq, qacc, piacc, pi_b2, dt,
                                        W, rowscale);
  gemm8_kernel<<<256, 512, 131072, stream>>>(W, XFT, rowscale, out);
}